// Round 6
// baseline (165.469 us; speedup 1.0000x reference)
//
#include <hip/hip_runtime.h>

#define TPB 256

// Fused CIoU, 2 threads per element. Even lane: P=A, Q=B; odd lane: P=B, Q=A.
// Both parities execute the SAME instruction stream (only base pointers
// differ) -> no divergence. Pair results merged with __shfl_xor(.,1).
//   - clip pass (Green's theorem edge intervals): each lane does its P's 8
//     edges vs Q's 8 half-planes; inter2 = self + partner.
//   - hull (Jarvis): each lane tree-scans its own 8 points; pair-merge picks
//     the more-clockwise candidate; cross(self,other) antisymmetry makes the
//     choice identical on both lanes.
// All state in named scalars (r3/r4: arrays => SROA failure => scratch).
__global__ __launch_bounds__(TPB, 4) void ciou_fused(
    const float* __restrict__ A,
    const float* __restrict__ Bq,
    float* __restrict__ out,
    double* __restrict__ acc,
    unsigned int* __restrict__ cnt,
    int nbatch, int nblocks)
{
    const int t = threadIdx.x;
    const long gtid = (long)blockIdx.x * TPB + t;
    int elem = (int)(gtid >> 1);
    const int par = (int)(gtid & 1);
    const bool live = (elem < nbatch);
    if (!live) elem = nbatch - 1;

    const float* baseP = par ? Bq : A;
    const float* baseQ = par ? A : Bq;

    float px0,px1,px2,px3,px4,px5,px6,px7;
    float py0,py1,py2,py3,py4,py5,py6,py7;
    float qx0,qx1,qx2,qx3,qx4,qx5,qx6,qx7;
    float qy0,qy1,qy2,qy3,qy4,qy5,qy6,qy7;
    {
        const float4* pp = (const float4*)(baseP + (size_t)elem * 16);
        const float4* pq = (const float4*)(baseQ + (size_t)elem * 16);
        float4 q;
        q = pp[0]; px0=q.x; py0=q.y; px1=q.z; py1=q.w;
        q = pp[1]; px2=q.x; py2=q.y; px3=q.z; py3=q.w;
        q = pp[2]; px4=q.x; py4=q.y; px5=q.z; py5=q.w;
        q = pp[3]; px6=q.x; py6=q.y; px7=q.z; py7=q.w;
        q = pq[0]; qx0=q.x; qy0=q.y; qx1=q.z; qy1=q.w;
        q = pq[1]; qx2=q.x; qy2=q.y; qx3=q.z; qy3=q.w;
        q = pq[2]; qx4=q.x; qy4=q.y; qx5=q.z; qy5=q.w;
        q = pq[3]; qx6=q.x; qy6=q.y; qx7=q.z; qy7=q.w;
    }

    // Shoelace of own polygon (CCW input; sort_poly is a pure rotation).
    float areaP = 0.5f * ((px0*py1-py0*px1) + (px1*py2-py1*px2)
                        + (px2*py3-py2*px3) + (px3*py4-py3*px4)
                        + (px4*py5-py4*px5) + (px5*py6-py5*px6)
                        + (px6*py7-py6*px7) + (px7*py0-py7*px0));
    float sumArea = areaP + __shfl_xor(areaP, 1);   // area_a + area_b (both lanes)

    // ---- Clip: own 8 edges vs Q's 8 half-planes (Green's theorem) ----
    const float INFP = __builtin_inff();
    float inter2s = 0.f;

#define HP(J,QX0,QY0,QX1,QY1) \
    float e0_##J, e1_##J; { \
        float ex = (QX1)-(QX0), ey = (QY1)-(QY0); \
        float aa = ex*(Py-(QY0)) - ey*(Px-(QX0)); \
        float bb = ex*Dy - ey*Dx; \
        float tc = __fdividef(-aa, bb); \
        e0_##J = (bb > 0.f) ? tc : -INFP; \
        e1_##J = (bb < 0.f) ? tc :  INFP; }

#define EDGE(PX,PY,NX,NY) { \
        const float Px = (PX), Py = (PY); \
        const float Dx = (NX) - Px, Dy = (NY) - Py; \
        HP(0,qx0,qy0,qx1,qy1) HP(1,qx1,qy1,qx2,qy2) \
        HP(2,qx2,qy2,qx3,qy3) HP(3,qx3,qy3,qx4,qy4) \
        HP(4,qx4,qy4,qx5,qy5) HP(5,qx5,qy5,qx6,qy6) \
        HP(6,qx6,qy6,qx7,qy7) HP(7,qx7,qy7,qx0,qy0) \
        float t0 = fmaxf(fmaxf(fmaxf(e0_0,e0_1), fmaxf(e0_2,e0_3)), \
                         fmaxf(fmaxf(e0_4,e0_5), fmaxf(e0_6,e0_7))); \
        float t1 = fminf(fminf(fminf(e1_0,e1_1), fminf(e1_2,e1_3)), \
                         fminf(fminf(e1_4,e1_5), fminf(e1_6,e1_7))); \
        t0 = fmaxf(t0, 0.f); t1 = fminf(t1, 1.f); \
        float P0x = fmaf(t0, Dx, Px), P0y = fmaf(t0, Dy, Py); \
        float P1x = fmaf(t1, Dx, Px), P1y = fmaf(t1, Dy, Py); \
        float cc = P0x*P1y - P0y*P1x; \
        inter2s += (t1 > t0) ? cc : 0.f; }

    EDGE(px0,py0,px1,py1) EDGE(px1,py1,px2,py2)
    EDGE(px2,py2,px3,py3) EDGE(px3,py3,px4,py4)
    EDGE(px4,py4,px5,py5) EDGE(px5,py5,px6,py6)
    EDGE(px6,py6,px7,py7) EDGE(px7,py7,px0,py0)

    float inter2 = inter2s + __shfl_xor(inter2s, 1);
    float inter = fmaxf(0.5f * inter2, 0.f);
    float uni = sumArea - inter;
    float iou = __fdividef(inter, uni);

    // ---- Hull start: min by (y, x) over own 8, then pair-merge ----
#define MINP(OX,OY,X1,Y1,X2,Y2) \
    float OX, OY; { bool s2 = ((Y2) < (Y1)) || (((Y2) == (Y1)) && ((X2) < (X1))); \
        OX = s2 ? (X2) : (X1); OY = s2 ? (Y2) : (Y1); }
    MINP(m0x,m0y, px0,py0, px1,py1)
    MINP(m1x,m1y, px2,py2, px3,py3)
    MINP(m2x,m2y, px4,py4, px5,py5)
    MINP(m3x,m3y, px6,py6, px7,py7)
    MINP(n0x,n0y, m0x,m0y, m1x,m1y)
    MINP(n1x,n1y, m2x,m2y, m3x,m3y)
    MINP(ssx,ssy, n0x,n0y, n1x,n1y)
    float osx = __shfl_xor(ssx, 1), osy = __shfl_xor(ssy, 1);
    MINP(stx,sty, ssx,ssy, osx,osy)

    // ---- Jarvis march: tree-scan own 8, pair-merge candidate ----
    float cxv = stx, cyv = sty, accH = 0.f;
    bool done = false;
    for (int it = 0; it < 16; ++it) {
#define LEAF(K,PX,PY) \
        float vxL##K = (PX) - cxv, vyL##K = (PY) - cyv; \
        bool vvL##K = (vxL##K*vxL##K + vyL##K*vyL##K) > 1e-16f;
        LEAF(0,px0,py0) LEAF(1,px1,py1) LEAF(2,px2,py2) LEAF(3,px3,py3)
        LEAF(4,px4,py4) LEAF(5,px5,py5) LEAF(6,px6,py6) LEAF(7,px7,py7)
        // level 1: leaves (K1,K2) -> node D   (take R iff R valid and
        // (L invalid or R strictly clockwise of L))
#define COMB1(D,K1,PX1,PY1,K2,PX2,PY2) \
        float vx##D, vy##D, wx##D, wy##D; bool vv##D; { \
            float cr = vxL##K1 * vyL##K2 - vyL##K1 * vxL##K2; \
            bool tk = vvL##K2 && (!vvL##K1 || cr < 0.f); \
            vx##D = tk ? vxL##K2 : vxL##K1;  vy##D = tk ? vyL##K2 : vyL##K1; \
            wx##D = tk ? (PX2) : (PX1);      wy##D = tk ? (PY2) : (PY1); \
            vv##D = vvL##K1 || vvL##K2; }
#define COMB(D,L,R) \
        float vx##D, vy##D, wx##D, wy##D; bool vv##D; { \
            float cr = vx##L * vy##R - vy##L * vx##R; \
            bool tk = vv##R && (!vv##L || cr < 0.f); \
            vx##D = tk ? vx##R : vx##L;  vy##D = tk ? vy##R : vy##L; \
            wx##D = tk ? wx##R : wx##L;  wy##D = tk ? wy##R : wy##L; \
            vv##D = vv##L || vv##R; }
        COMB1(a0, 0,px0,py0, 1,px1,py1)
        COMB1(a1, 2,px2,py2, 3,px3,py3)
        COMB1(a2, 4,px4,py4, 5,px5,py5)
        COMB1(a3, 6,px6,py6, 7,px7,py7)
        COMB(b0, a0, a1)
        COMB(b1, a2, a3)
        COMB(r_, b0, b1)
        // pair-merge: partner candidate (always valid: own set has >=7
        // distinct points). cross antisymmetry -> identical pick on both lanes.
        float ovx = __shfl_xor(vxr_, 1), ovy = __shfl_xor(vyr_, 1);
        float owx = __shfl_xor(wxr_, 1), owy = __shfl_xor(wyr_, 1);
        float crm = vxr_ * ovy - vyr_ * ovx;
        bool tko = (crm < 0.f);
        float nx = tko ? owx : wxr_;
        float ny = tko ? owy : wyr_;
        accH += done ? 0.f : (cxv * ny - cyv * nx);
        done = done || (nx == stx && ny == sty);
        cxv = nx; cyv = ny;
        if (__all(done)) break;
    }
    float ch = 0.5f * accH;

    float val = iou - __fdividef(ch - uni, ch);
    float v = live ? 0.5f * val : 0.f;   // pair sums to val exactly

    // ---- reduction: wave shuffle -> LDS(16B) -> global double atomic ----
    #pragma unroll
    for (int off = 32; off > 0; off >>= 1) v += __shfl_down(v, off);
    __shared__ float wsum[4];
    int lane = t & 63, wid = t >> 6;
    if (lane == 0) wsum[wid] = v;
    __syncthreads();
    if (t == 0) {
        double bsum = (double)wsum[0] + (double)wsum[1]
                    + (double)wsum[2] + (double)wsum[3];
        atomicAdd(acc, bsum);
        __threadfence();
        unsigned int old = atomicAdd(cnt, 1u);
        if (old == (unsigned int)(nblocks - 1)) {
            double total = atomicAdd(acc, 0.0);   // read after all adds visible
            out[0] = (float)(total / (double)nbatch);
        }
    }
}

extern "C" void kernel_launch(void* const* d_in, const int* in_sizes, int n_in,
                              void* d_out, int out_size, void* d_ws, size_t ws_size,
                              hipStream_t stream) {
    const float* a = (const float*)d_in[0];
    const float* b = (const float*)d_in[1];
    float* out = (float*)d_out;
    int nbatch = in_sizes[0] / 16;
    long nthreads = 2L * nbatch;
    int nblocks = (int)((nthreads + TPB - 1) / TPB);
    double* acc = (double*)d_ws;                          // [0,8): double sum
    unsigned int* cnt = (unsigned int*)((char*)d_ws + 8); // [8,12): counter
    hipMemsetAsync(d_ws, 0, 16, stream);
    ciou_fused<<<nblocks, TPB, 0, stream>>>(a, b, out, acc, cnt, nbatch, nblocks);
}